// Round 1
// baseline (236.530 us; speedup 1.0000x reference)
//
#include <hip/hip_runtime.h>

namespace {

constexpr int BATCH = 256;
constexpr int DCAPS = 10;
constexpr int PCAPS = 1152;
constexpr int ODIM  = 16;
constexpr int IDIM  = 8;
constexpr float EPS_ = 1e-7f;

constexpr int PC   = 36;            // p's per workgroup
constexpr int NPB  = PCAPS / PC;    // 32
constexpr int BBLK = 16;            // b's per workgroup (one per 16-lane group)
constexpr int NBB  = BATCH / BBLK;  // 16

// Routing pass. NV = how many v-vectors feed the logits (0 -> uniform c=0.1).
// Each 16-lane group handles one b; lane = output dim o. Loops over PC p's,
// recomputing u_hat[10][16] on the fly, softmax over D in-register,
// accumulating s partials in registers, atomicAdd at the end.
template <int NV>
__global__ __launch_bounds__(256)
void route_kernel(const float* __restrict__ x, const float* __restrict__ W,
                  const float* __restrict__ v0, const float* __restrict__ v1,
                  float* __restrict__ s_out)
{
    const int tid  = threadIdx.x;
    const int g    = tid >> 4;          // lane-group within block (0..15) -> b
    const int o    = tid & 15;          // output dim
    const int bBlk = blockIdx.x % NBB;  // b fast-varying for W reuse across XCDs
    const int pBlk = blockIdx.x / NBB;
    const int b    = bBlk * BBLK + g;
    const int p0   = pBlk * PC;

    // preload v[b, d, o] (sum of the provided v's, since uv0+uv1 = uv(v0+v1))
    float vr[DCAPS];
    if constexpr (NV >= 1) {
#pragma unroll
        for (int d = 0; d < DCAPS; ++d) {
            float t = v0[(b * DCAPS + d) * ODIM + o];
            if constexpr (NV == 2) t += v1[(b * DCAPS + d) * ODIM + o];
            vr[d] = t;
        }
    }

    float s_acc[DCAPS];
#pragma unroll
    for (int d = 0; d < DCAPS; ++d) s_acc[d] = 0.f;

    for (int p = p0; p < p0 + PC; ++p) {
        // x[b,p,0:8] -- same 32B for all 16 lanes of the group (L1 broadcast)
        const float4* xp = reinterpret_cast<const float4*>(x + ((size_t)b * PCAPS + p) * IDIM);
        const float4 xa = xp[0];
        const float4 xb = xp[1];

        // u_hat[d] for this lane's o: dot8(W[d,p,o,:], x[b,p,:])
        float uh[DCAPS];
#pragma unroll
        for (int d = 0; d < DCAPS; ++d) {
            const float4* wp = reinterpret_cast<const float4*>(
                W + (((size_t)d * PCAPS + p) * ODIM + o) * IDIM);
            const float4 wa = wp[0];
            const float4 wb = wp[1];
            float acc;
            acc = wa.x * xa.x;
            acc = fmaf(wa.y, xa.y, acc);
            acc = fmaf(wa.z, xa.z, acc);
            acc = fmaf(wa.w, xa.w, acc);
            acc = fmaf(wb.x, xb.x, acc);
            acc = fmaf(wb.y, xb.y, acc);
            acc = fmaf(wb.z, xb.z, acc);
            acc = fmaf(wb.w, xb.w, acc);
            uh[d] = acc;
        }

        float c[DCAPS];
        if constexpr (NV == 0) {
#pragma unroll
            for (int d = 0; d < DCAPS; ++d) c[d] = 0.1f;
        } else {
            // logits: b[d] = sum_o u_hat[d][o] * vr[d][o]  (reduce across 16 lanes)
            float logit[DCAPS];
#pragma unroll
            for (int d = 0; d < DCAPS; ++d) {
                float t = uh[d] * vr[d];
                t += __shfl_xor(t, 1, 16);
                t += __shfl_xor(t, 2, 16);
                t += __shfl_xor(t, 4, 16);
                t += __shfl_xor(t, 8, 16);
                logit[d] = t;
            }
            // softmax over D=10 (redundantly in every lane)
            float mx = logit[0];
#pragma unroll
            for (int d = 1; d < DCAPS; ++d) mx = fmaxf(mx, logit[d]);
            float ssum = 0.f;
#pragma unroll
            for (int d = 0; d < DCAPS; ++d) {
                c[d] = __expf(logit[d] - mx);
                ssum += c[d];
            }
            const float inv = 1.0f / ssum;
#pragma unroll
            for (int d = 0; d < DCAPS; ++d) c[d] *= inv;
        }

#pragma unroll
        for (int d = 0; d < DCAPS; ++d) s_acc[d] = fmaf(c[d], uh[d], s_acc[d]);
    }

#pragma unroll
    for (int d = 0; d < DCAPS; ++d)
        atomicAdd(&s_out[(b * DCAPS + d) * ODIM + o], s_acc[d]);
}

// squash over the last (O=16) axis; one thread per (b,d)
__global__ __launch_bounds__(256)
void squash_kernel(const float* __restrict__ s, float* __restrict__ out)
{
    const int idx = blockIdx.x * 256 + threadIdx.x;
    if (idx >= BATCH * DCAPS) return;
    const float4* sp = reinterpret_cast<const float4*>(s + (size_t)idx * ODIM);
    float4 a = sp[0], b4 = sp[1], c4 = sp[2], d4 = sp[3];
    float sq = a.x * a.x + a.y * a.y + a.z * a.z + a.w * a.w
             + b4.x * b4.x + b4.y * b4.y + b4.z * b4.z + b4.w * b4.w
             + c4.x * c4.x + c4.y * c4.y + c4.z * c4.z + c4.w * c4.w
             + d4.x * d4.x + d4.y * d4.y + d4.z * d4.z + d4.w * d4.w;
    const float scale = (sq / (1.0f + sq)) / sqrtf(sq + EPS_);
    a.x *= scale; a.y *= scale; a.z *= scale; a.w *= scale;
    b4.x *= scale; b4.y *= scale; b4.z *= scale; b4.w *= scale;
    c4.x *= scale; c4.y *= scale; c4.z *= scale; c4.w *= scale;
    d4.x *= scale; d4.y *= scale; d4.z *= scale; d4.w *= scale;
    float4* op = reinterpret_cast<float4*>(out + (size_t)idx * ODIM);
    op[0] = a; op[1] = b4; op[2] = c4; op[3] = d4;
}

} // namespace

extern "C" void kernel_launch(void* const* d_in, const int* in_sizes, int n_in,
                              void* d_out, int out_size, void* d_ws, size_t ws_size,
                              hipStream_t stream)
{
    const float* x = (const float*)d_in[0];   // [256, 1152, 8]
    const float* W = (const float*)d_in[1];   // [1, 10, 1152, 16, 8]
    float* out = (float*)d_out;               // [256, 10, 16]

    constexpr size_t SDO = (size_t)BATCH * DCAPS * ODIM;  // 40960
    float* s_buf = (float*)d_ws;
    float* v0    = s_buf + SDO;
    float* v1    = v0 + SDO;

    const dim3 blk(256);
    const dim3 rgrid(NBB * NPB);                       // 512
    const dim3 sgrid((BATCH * DCAPS + 255) / 256);     // 10

    // pass 0: c uniform 0.1 -> s0 -> v0
    hipMemsetAsync(s_buf, 0, SDO * sizeof(float), stream);
    route_kernel<0><<<rgrid, blk, 0, stream>>>(x, W, nullptr, nullptr, s_buf);
    squash_kernel<<<sgrid, blk, 0, stream>>>(s_buf, v0);

    // pass 1: logits = uv(v0) -> s1 -> v1
    hipMemsetAsync(s_buf, 0, SDO * sizeof(float), stream);
    route_kernel<1><<<rgrid, blk, 0, stream>>>(x, W, v0, nullptr, s_buf);
    squash_kernel<<<sgrid, blk, 0, stream>>>(s_buf, v1);

    // pass 2: logits = uv(v0)+uv(v1) = uv(v0+v1) -> s2 -> out
    hipMemsetAsync(s_buf, 0, SDO * sizeof(float), stream);
    route_kernel<2><<<rgrid, blk, 0, stream>>>(x, W, v0, v1, s_buf);
    squash_kernel<<<sgrid, blk, 0, stream>>>(s_buf, out);
}